// Round 6
// baseline (1022.969 us; speedup 1.0000x reference)
//
#include <hip/hip_runtime.h>
#include <hip/hip_fp16.h>

#define IN_F 128
#define H_F 64
#define C_F 16
#define BUCKET 64           // dst-nodes per bucket
#define BSH 6               // log2(BUCKET)
#define MAXB 2048           // hist/scan capacity (>= nBuckets = ceil(N/64))
#define EPB 16384           // edges per k_bin block
#define CAP 2048            // staged codes per k_agg block

// ---------------- degree histograms ----------------
__global__ void k_degrees(const int* __restrict__ src, const int* __restrict__ dst,
                          int* __restrict__ degi_out, int* __restrict__ degi_in, int E) {
    int e = blockIdx.x * 256 + threadIdx.x;
    if (e < E) {
        atomicAdd(&degi_out[src[e]], 1);
        atomicAdd(&degi_in[dst[e]], 1);
    }
}

// ---------------- norms ----------------
__global__ void k_norms(const int* __restrict__ degi_out, const int* __restrict__ degi_in,
                        float* __restrict__ norm_out, float* __restrict__ norm_in, int N) {
    int n = blockIdx.x * 256 + threadIdx.x;
    if (n < N) {
        norm_out[n] = 1.0f / sqrtf((float)max(degi_out[n], 1));
        norm_in[n]  = 1.0f / sqrtf((float)max(degi_in[n], 1));
    }
}

// ---------------- per-bucket edge counts (wave per 64-node bucket) ----------------
__global__ __launch_bounds__(256) void k_bucketcnt(const int* __restrict__ degi_in,
                                                   int* __restrict__ bucketCnt, int N, int nb) {
    const int wave = threadIdx.x >> 6, lane = threadIdx.x & 63;
    int b = blockIdx.x * 4 + wave;
    if (b >= nb) return;
    int n = b * BUCKET + lane;
    int v = (n < N) ? degi_in[n] : 0;
    for (int off = 32; off; off >>= 1) v += __shfl_xor(v, off);
    if (lane == 0) bucketCnt[b] = v;
}

// ---------------- exclusive scan of bucket counts (single block, 2 elems/thread) ------
__global__ __launch_bounds__(1024) void k_bucketscan(const int* __restrict__ bucketCnt,
                                                     int* __restrict__ bucketBase,
                                                     int* __restrict__ gCursor, int nb, int E) {
    __shared__ int s[1024];
    int t = threadIdx.x;
    int i0 = 2 * t, i1 = 2 * t + 1;
    int v0 = (i0 < nb) ? bucketCnt[i0] : 0;
    int v1 = (i1 < nb) ? bucketCnt[i1] : 0;
    int pair = v0 + v1;
    s[t] = pair;
    __syncthreads();
    for (int off = 1; off < 1024; off <<= 1) {
        int x = (t >= off) ? s[t - off] : 0;
        __syncthreads();
        s[t] += x;
        __syncthreads();
    }
    int excl = s[t] - pair;
    if (i0 < nb) { bucketBase[i0] = excl;      gCursor[i0] = excl; }
    if (i1 < nb) { bucketBase[i1] = excl + v0; gCursor[i1] = excl + v0; }
    if (t == 0) bucketBase[nb] = E;
}

// ---------------- bin edges by 64-node bucket + wsum[s] += norm_in[d] ----------------
// code = (dlocal << 17) | src   (src < 2^17, dlocal < 64)
__global__ __launch_bounds__(256) void k_bin(const int* __restrict__ src,
                                             const int* __restrict__ dst,
                                             const float* __restrict__ norm_in,
                                             float* __restrict__ wsum,
                                             int* __restrict__ gCursor,
                                             unsigned int* __restrict__ binned,
                                             int E, int nb) {
    __shared__ int hist[MAXB];
    __shared__ int base[MAXB];
    __shared__ int cur[MAXB];
    const int tid = threadIdx.x;
    const int start = blockIdx.x * EPB;
    for (int i = tid; i < MAXB; i += 256) { hist[i] = 0; cur[i] = 0; }
    __syncthreads();
#pragma unroll 4
    for (int k = 0; k < EPB / 256; ++k) {
        int e = start + (k << 8) + tid;
        if (e < E) atomicAdd(&hist[dst[e] >> BSH], 1);
    }
    __syncthreads();
    for (int b = tid; b < nb; b += 256)
        if (hist[b]) base[b] = atomicAdd(&gCursor[b], hist[b]);
    __syncthreads();
    for (int k = 0; k < EPB / 256; ++k) {
        int e = start + (k << 8) + tid;
        if (e < E) {
            int s = src[e], d = dst[e];
            int b = d >> BSH;
            int p = base[b] + atomicAdd(&cur[b], 1);
            binned[p] = ((unsigned)(d & (BUCKET - 1)) << 17) | (unsigned)s;
            atomicAdd(&wsum[s], norm_in[d]);
        }
    }
}

// ---------------- layer 1 GEMM: X1h = fp16((in_feat @ W1) * norm_out), [N,64] ----------
__global__ __launch_bounds__(256) void k_gemm1(const float* __restrict__ in_feat,
                                               const float* __restrict__ W1,
                                               const float* __restrict__ norm_out,
                                               __half* __restrict__ X1h, int N) {
    __shared__ float Wl[IN_F][H_F];       // 32 KB
    __shared__ float Al[64][IN_F + 4];    // 33 KB
    const int t = threadIdx.x;
    const int base = blockIdx.x * 64;

    for (int i = t; i < IN_F * H_F / 4; i += 256)
        ((float4*)&Wl[0][0])[i] = ((const float4*)W1)[i];
    for (int i = t; i < 64 * IN_F / 4; i += 256) {
        int n = i >> 5;
        int k4 = i & 31;
        int gn = base + n;
        float4 v = make_float4(0.f, 0.f, 0.f, 0.f);
        if (gn < N) v = ((const float4*)(in_feat + (size_t)gn * IN_F))[k4];
        *(float4*)&Al[n][k4 * 4] = v;
    }
    __syncthreads();

    const int c4 = (t & 15) * 4;
    const int r4 = (t >> 4) * 4;
    float acc[4][4] = {};
#pragma unroll 4
    for (int k = 0; k < IN_F; k += 4) {
        float4 w0 = *(const float4*)&Wl[k + 0][c4];
        float4 w1 = *(const float4*)&Wl[k + 1][c4];
        float4 w2 = *(const float4*)&Wl[k + 2][c4];
        float4 w3 = *(const float4*)&Wl[k + 3][c4];
        const float* wp0 = (const float*)&w0;
        const float* wp1 = (const float*)&w1;
        const float* wp2 = (const float*)&w2;
        const float* wp3 = (const float*)&w3;
#pragma unroll
        for (int i = 0; i < 4; ++i) {
            float4 a = *(const float4*)&Al[r4 + i][k];
#pragma unroll
            for (int jj = 0; jj < 4; ++jj)
                acc[i][jj] = fmaf(a.x, wp0[jj],
                             fmaf(a.y, wp1[jj],
                             fmaf(a.z, wp2[jj],
                             fmaf(a.w, wp3[jj], acc[i][jj]))));
        }
    }
#pragma unroll
    for (int i = 0; i < 4; ++i) {
        int n = base + r4 + i;
        if (n < N) {
            float no = norm_out[n];
            __half2 p0 = __floats2half2_rn(acc[i][0] * no, acc[i][1] * no);
            __half2 p1 = __floats2half2_rn(acc[i][2] * no, acc[i][3] * no);
            __half2* dp = (__half2*)&X1h[(size_t)n * H_F + c4];
            dp[0] = p0; dp[1] = p1;
        }
    }
}

// ---- fused aggregation: per-64-node-bucket LDS accumulate + relu/bias + weighted colsum
// block = bucket (64 nodes). acc[64][64] fp32 (16KB) + staged codes (8KB).
__global__ __launch_bounds__(256) void k_agg(const __half* __restrict__ X1h,
                                             const unsigned int* __restrict__ binned,
                                             const int* __restrict__ bucketBase,
                                             const float* __restrict__ norm_in,
                                             const float* __restrict__ norm_out,
                                             const float* __restrict__ wsum,
                                             const float* __restrict__ b1,
                                             float* __restrict__ partials, int N) {
    __shared__ float acc[BUCKET * H_F];   // 16 KB
    __shared__ unsigned cds[CAP];         // 8 KB
    __shared__ float hl[4][64];
    const int tid = threadIdx.x, lane = tid & 63, wave = tid >> 6;

    for (int i = tid; i < BUCKET * H_F / 4; i += 256)
        ((float4*)acc)[i] = make_float4(0.f, 0.f, 0.f, 0.f);

    const int base = bucketBase[blockIdx.x];
    const int cnt  = bucketBase[blockIdx.x + 1] - base;
    const int stg  = cnt < CAP ? cnt : CAP;
    for (int i = tid; i < stg; i += 256) cds[i] = binned[base + i];
    __syncthreads();

    // 8 edges per wave-iteration: all gathers issued before any LDS add
    for (int e0 = wave * 8; e0 < cnt; e0 += 32) {
        unsigned cc[8];
        float vv[8];
        int dd[8];
#pragma unroll
        for (int u = 0; u < 8; ++u) {
            int e = e0 + u;
            cc[u] = (e < cnt) ? ((e < CAP) ? cds[e] : binned[base + e]) : 0u;
        }
#pragma unroll
        for (int u = 0; u < 8; ++u) {
            int e = e0 + u;
            int s = (int)(cc[u] & 0x1FFFFu);
            dd[u] = (int)(cc[u] >> 17);
            vv[u] = (e < cnt) ? __half2float(X1h[(size_t)s * H_F + lane]) : 0.0f;
        }
#pragma unroll
        for (int u = 0; u < 8; ++u)
            atomicAdd(&acc[dd[u] * H_F + lane], vv[u]);
    }
    __syncthreads();

    // epilogue: wave w handles nodes w*16 .. w*16+15; lane = feature
    const float bj = b1[lane];
    const int gbase = blockIdx.x * BUCKET;
    float hacc = 0.0f;
#pragma unroll 4
    for (int k = 0; k < 16; ++k) {
        int nl = wave * 16 + k;
        int gn = gbase + nl;
        if (gn < N) {
            float v = acc[nl * H_F + lane] * norm_in[gn] + bj;
            hacc = fmaf(v > 0.0f ? v : 0.0f, norm_out[gn] * wsum[gn], hacc);
        }
    }
    hl[wave][lane] = hacc;
    __syncthreads();
    if (wave == 0)
        partials[(size_t)blockIdx.x * 64 + lane] =
            (hl[0][lane] + hl[1][lane]) + (hl[2][lane] + hl[3][lane]);
}

// ---------------- final: hsum (f64) -> out = hsum@W2/N + b2 ----------------
__global__ __launch_bounds__(256) void k_final(const float* __restrict__ partials,
                                               const float* __restrict__ W2,
                                               const float* __restrict__ b2,
                                               float* __restrict__ out, int nb, int N) {
    __shared__ double hs[4][64];
    const int sub = threadIdx.x >> 6;   // 0..3
    const int j   = threadIdx.x & 63;
    double s = 0.0;
    for (int p = sub; p < nb; p += 4)
        s += (double)partials[(size_t)p * 64 + j];
    hs[sub][j] = s;
    __syncthreads();
    if (threadIdx.x < C_F) {
        int c = threadIdx.x;
        double o = 0.0;
        for (int k = 0; k < 64; ++k) {
            double hk = hs[0][k] + hs[1][k] + hs[2][k] + hs[3][k];
            o += hk * (double)W2[k * C_F + c];
        }
        out[c] = (float)(o / (double)N + (double)b2[c]);
    }
}

extern "C" void kernel_launch(void* const* d_in, const int* in_sizes, int n_in,
                              void* d_out, int out_size, void* d_ws, size_t ws_size,
                              hipStream_t stream) {
    const float* in_feat = (const float*)d_in[0];
    const int*   src     = (const int*)d_in[1];
    const int*   dst     = (const int*)d_in[2];
    const float* W1      = (const float*)d_in[3];
    const float* b1      = (const float*)d_in[4];
    const float* W2      = (const float*)d_in[5];
    const float* b2      = (const float*)d_in[6];
    float* out = (float*)d_out;

    const int N = in_sizes[0] / IN_F;           // 100000
    const int E = in_sizes[1];                  // 1600000
    const int nb = (N + BUCKET - 1) / BUCKET;   // 1563 (<= MAXB)

    // ---- workspace layout (4B units) ----
    unsigned int* binned = (unsigned int*)d_ws;          // E
    int*   degi_out  = (int*)(binned + E);               // N
    int*   degi_in   = degi_out + N;                     // N
    float* wsum      = (float*)(degi_in + N);            // N (zeroed with degrees)
    float* norm_out  = wsum + N;                         // N
    float* norm_in   = norm_out + N;                     // N
    int*   bucketCnt = (int*)(norm_in + N);              // MAXB
    int*   bucketBase= bucketCnt + MAXB;                 // MAXB+1
    int*   gCursor   = bucketBase + MAXB + 1;            // MAXB (+3 pad)
    __half* X1h      = (__half*)(gCursor + MAXB + 3);    // 64N halves
    float* partials  = (float*)(X1h + 64 * (size_t)N);   // nb*64

    // degrees + wsum are read-before-write (contiguous 3N)
    hipMemsetAsync(degi_out, 0, 3 * (size_t)N * sizeof(int), stream);

    k_degrees<<<(E + 255) / 256, 256, 0, stream>>>(src, dst, degi_out, degi_in, E);
    k_norms  <<<(N + 255) / 256, 256, 0, stream>>>(degi_out, degi_in, norm_out, norm_in, N);

    k_bucketcnt <<<(nb + 3) / 4, 256, 0, stream>>>(degi_in, bucketCnt, N, nb);
    k_bucketscan<<<1, 1024, 0, stream>>>(bucketCnt, bucketBase, gCursor, nb, E);

    k_bin<<<(E + EPB - 1) / EPB, 256, 0, stream>>>(src, dst, norm_in, wsum, gCursor,
                                                   binned, E, nb);

    k_gemm1<<<(N + 63) / 64, 256, 0, stream>>>(in_feat, W1, norm_out, X1h, N);

    k_agg<<<nb, 256, 0, stream>>>(X1h, binned, bucketBase, norm_in, norm_out,
                                  wsum, b1, partials, N);

    k_final<<<1, 256, 0, stream>>>(partials, W2, b2, out, nb, N);
}

// Round 7
// 437.206 us; speedup vs baseline: 2.3398x; 2.3398x over previous
//
#include <hip/hip_runtime.h>
#include <hip/hip_fp16.h>

#define IN_F 128
#define H_F 64
#define C_F 16
#define BUCKET 64           // dst-nodes per bucket
#define BSH 6               // log2(BUCKET)
#define MAXB 2048           // hist/scan capacity (>= nBuckets = ceil(N/64))
#define EPB 8192            // edges per k_bin block
#define CAP 2048            // staged codes per k_agg block

// ---------------- degree histograms ----------------
__global__ void k_degrees(const int* __restrict__ src, const int* __restrict__ dst,
                          int* __restrict__ degi_out, int* __restrict__ degi_in, int E) {
    int e = blockIdx.x * 256 + threadIdx.x;
    if (e < E) {
        atomicAdd(&degi_out[src[e]], 1);
        atomicAdd(&degi_in[dst[e]], 1);
    }
}

// ---------------- norms ----------------
__global__ void k_norms(const int* __restrict__ degi_out, const int* __restrict__ degi_in,
                        float* __restrict__ norm_out, float* __restrict__ norm_in, int N) {
    int n = blockIdx.x * 256 + threadIdx.x;
    if (n < N) {
        norm_out[n] = 1.0f / sqrtf((float)max(degi_out[n], 1));
        norm_in[n]  = 1.0f / sqrtf((float)max(degi_in[n], 1));
    }
}

// ---------------- per-bucket edge counts (wave per 64-node bucket) ----------------
__global__ __launch_bounds__(256) void k_bucketcnt(const int* __restrict__ degi_in,
                                                   int* __restrict__ bucketCnt, int N, int nb) {
    const int wave = threadIdx.x >> 6, lane = threadIdx.x & 63;
    int b = blockIdx.x * 4 + wave;
    if (b >= nb) return;
    int n = b * BUCKET + lane;
    int v = (n < N) ? degi_in[n] : 0;
    for (int off = 32; off; off >>= 1) v += __shfl_xor(v, off);
    if (lane == 0) bucketCnt[b] = v;
}

// ---------------- exclusive scan of bucket counts (single block, 2 elems/thread) ------
__global__ __launch_bounds__(1024) void k_bucketscan(const int* __restrict__ bucketCnt,
                                                     int* __restrict__ bucketBase,
                                                     int* __restrict__ gCursor, int nb, int E) {
    __shared__ int s[1024];
    int t = threadIdx.x;
    int i0 = 2 * t, i1 = 2 * t + 1;
    int v0 = (i0 < nb) ? bucketCnt[i0] : 0;
    int v1 = (i1 < nb) ? bucketCnt[i1] : 0;
    int pair = v0 + v1;
    s[t] = pair;
    __syncthreads();
    for (int off = 1; off < 1024; off <<= 1) {
        int x = (t >= off) ? s[t - off] : 0;
        __syncthreads();
        s[t] += x;
        __syncthreads();
    }
    int excl = s[t] - pair;
    if (i0 < nb) { bucketBase[i0] = excl;      gCursor[i0] = excl; }
    if (i1 < nb) { bucketBase[i1] = excl + v0; gCursor[i1] = excl + v0; }
    if (t == 0) bucketBase[nb] = E;
}

// ---------------- bin edges by 64-node bucket + wsum[s] += norm_in[d] ----------------
// code = (dlocal << 17) | src   (src < 2^17, dlocal < 64)
__global__ __launch_bounds__(256) void k_bin(const int* __restrict__ src,
                                             const int* __restrict__ dst,
                                             const float* __restrict__ norm_in,
                                             float* __restrict__ wsum,
                                             int* __restrict__ gCursor,
                                             unsigned int* __restrict__ binned,
                                             int E, int nb) {
    __shared__ int hist[MAXB];
    __shared__ int base[MAXB];
    __shared__ int cur[MAXB];
    const int tid = threadIdx.x;
    const int start = blockIdx.x * EPB;
    for (int i = tid; i < MAXB; i += 256) { hist[i] = 0; cur[i] = 0; }
    __syncthreads();
#pragma unroll 4
    for (int k = 0; k < EPB / 256; ++k) {
        int e = start + (k << 8) + tid;
        if (e < E) atomicAdd(&hist[dst[e] >> BSH], 1);
    }
    __syncthreads();
    for (int b = tid; b < nb; b += 256)
        if (hist[b]) base[b] = atomicAdd(&gCursor[b], hist[b]);
    __syncthreads();
    for (int k = 0; k < EPB / 256; ++k) {
        int e = start + (k << 8) + tid;
        if (e < E) {
            int s = src[e], d = dst[e];
            int b = d >> BSH;
            int p = base[b] + atomicAdd(&cur[b], 1);
            binned[p] = ((unsigned)(d & (BUCKET - 1)) << 17) | (unsigned)s;
            atomicAdd(&wsum[s], norm_in[d]);
        }
    }
}

// ---------------- layer 1 GEMM: X1h = fp16((in_feat @ W1) * norm_out), [N,64] ----------
__global__ __launch_bounds__(256) void k_gemm1(const float* __restrict__ in_feat,
                                               const float* __restrict__ W1,
                                               const float* __restrict__ norm_out,
                                               __half* __restrict__ X1h, int N) {
    __shared__ float Wl[IN_F][H_F];       // 32 KB
    __shared__ float Al[64][IN_F + 4];    // 33 KB
    const int t = threadIdx.x;
    const int base = blockIdx.x * 64;

    for (int i = t; i < IN_F * H_F / 4; i += 256)
        ((float4*)&Wl[0][0])[i] = ((const float4*)W1)[i];
    for (int i = t; i < 64 * IN_F / 4; i += 256) {
        int n = i >> 5;
        int k4 = i & 31;
        int gn = base + n;
        float4 v = make_float4(0.f, 0.f, 0.f, 0.f);
        if (gn < N) v = ((const float4*)(in_feat + (size_t)gn * IN_F))[k4];
        *(float4*)&Al[n][k4 * 4] = v;
    }
    __syncthreads();

    const int c4 = (t & 15) * 4;
    const int r4 = (t >> 4) * 4;
    float acc[4][4] = {};
#pragma unroll 4
    for (int k = 0; k < IN_F; k += 4) {
        float4 w0 = *(const float4*)&Wl[k + 0][c4];
        float4 w1 = *(const float4*)&Wl[k + 1][c4];
        float4 w2 = *(const float4*)&Wl[k + 2][c4];
        float4 w3 = *(const float4*)&Wl[k + 3][c4];
        const float* wp0 = (const float*)&w0;
        const float* wp1 = (const float*)&w1;
        const float* wp2 = (const float*)&w2;
        const float* wp3 = (const float*)&w3;
#pragma unroll
        for (int i = 0; i < 4; ++i) {
            float4 a = *(const float4*)&Al[r4 + i][k];
#pragma unroll
            for (int jj = 0; jj < 4; ++jj)
                acc[i][jj] = fmaf(a.x, wp0[jj],
                             fmaf(a.y, wp1[jj],
                             fmaf(a.z, wp2[jj],
                             fmaf(a.w, wp3[jj], acc[i][jj]))));
        }
    }
#pragma unroll
    for (int i = 0; i < 4; ++i) {
        int n = base + r4 + i;
        if (n < N) {
            float no = norm_out[n];
            __half2 p0 = __floats2half2_rn(acc[i][0] * no, acc[i][1] * no);
            __half2 p1 = __floats2half2_rn(acc[i][2] * no, acc[i][3] * no);
            __half2* dp = (__half2*)&X1h[(size_t)n * H_F + c4];
            dp[0] = p0; dp[1] = p1;
        }
    }
}

// ---- fused aggregation: in-LDS counting sort by dlocal + REGISTER accumulation -------
// block = bucket (64 nodes); wave w owns nodes [w*16, w*16+16); lane = feature.
__global__ __launch_bounds__(256) void k_agg(const __half* __restrict__ X1h,
                                             const unsigned int* __restrict__ binned,
                                             const int* __restrict__ bucketBase,
                                             const float* __restrict__ norm_in,
                                             const float* __restrict__ norm_out,
                                             const float* __restrict__ wsum,
                                             const float* __restrict__ b1,
                                             float* __restrict__ partials, int N) {
    __shared__ union {
        struct { unsigned cds[CAP]; unsigned cds2[CAP]; } f;   // 16 KB
        float acc[BUCKET * H_F];                               // 16 KB (fallback)
    } u;
    __shared__ int hist[BUCKET];
    __shared__ int cur[BUCKET];
    __shared__ int loff[BUCKET + 1];
    __shared__ float hl[4][64];
    const int tid = threadIdx.x, lane = tid & 63, wave = tid >> 6;
    const int base = bucketBase[blockIdx.x];
    const int cnt  = bucketBase[blockIdx.x + 1] - base;
    const int gbase = blockIdx.x * BUCKET;
    const float bj = b1[lane];
    float hacc = 0.0f;

    if (cnt <= CAP) {
        // ---------- fast path ----------
        if (tid < BUCKET) hist[tid] = 0;
        __syncthreads();
        for (int i = tid; i < cnt; i += 256) {
            unsigned c = binned[base + i];
            u.f.cds[i] = c;
            atomicAdd(&hist[c >> 17], 1);
        }
        __syncthreads();
        if (wave == 0) {
            int v = hist[lane];
            int inc = v;
#pragma unroll
            for (int off = 1; off < 64; off <<= 1) {
                int t2 = __shfl_up(inc, off);
                if (lane >= off) inc += t2;
            }
            loff[lane + 1] = inc;
            cur[lane] = inc - v;          // exclusive prefix
            if (lane == 0) loff[0] = 0;
        }
        __syncthreads();
        for (int i = tid; i < cnt; i += 256) {
            unsigned c = u.f.cds[i];
            int p = atomicAdd(&cur[c >> 17], 1);
            u.f.cds2[p] = c;
        }
        __syncthreads();
        for (int k = 0; k < 16; ++k) {
            int nl = wave * 16 + k;
            int gn = gbase + nl;
            if (gn >= N) break;
            int s0 = loff[nl], s1 = loff[nl + 1];
            float acc = 0.0f;
            int e = s0;
            for (; e + 3 < s1; e += 4) {
                int sa = (int)(u.f.cds2[e]     & 0x1FFFFu);
                int sb = (int)(u.f.cds2[e + 1] & 0x1FFFFu);
                int sc = (int)(u.f.cds2[e + 2] & 0x1FFFFu);
                int sd = (int)(u.f.cds2[e + 3] & 0x1FFFFu);
                float a0 = __half2float(X1h[(size_t)sa * H_F + lane]);
                float a1 = __half2float(X1h[(size_t)sb * H_F + lane]);
                float a2 = __half2float(X1h[(size_t)sc * H_F + lane]);
                float a3 = __half2float(X1h[(size_t)sd * H_F + lane]);
                acc += (a0 + a1) + (a2 + a3);
            }
            for (; e < s1; ++e)
                acc += __half2float(X1h[(size_t)(u.f.cds2[e] & 0x1FFFFu) * H_F + lane]);
            float v = acc * norm_in[gn] + bj;
            hacc = fmaf(v > 0.0f ? v : 0.0f, norm_out[gn] * wsum[gn], hacc);
        }
    } else {
        // ---------- fallback (cnt > CAP; statistically never for this graph) ----------
        for (int i = tid; i < BUCKET * H_F / 4; i += 256)
            ((float4*)u.acc)[i] = make_float4(0.f, 0.f, 0.f, 0.f);
        __syncthreads();
        for (int e0 = wave * 8; e0 < cnt; e0 += 32) {
            unsigned cc[8];
            float vv[8];
            int dd[8];
#pragma unroll
            for (int v2 = 0; v2 < 8; ++v2) {
                int e = e0 + v2;
                cc[v2] = (e < cnt) ? binned[base + e] : 0u;
            }
#pragma unroll
            for (int v2 = 0; v2 < 8; ++v2) {
                int e = e0 + v2;
                int s = (int)(cc[v2] & 0x1FFFFu);
                dd[v2] = (int)(cc[v2] >> 17);
                vv[v2] = (e < cnt) ? __half2float(X1h[(size_t)s * H_F + lane]) : 0.0f;
            }
#pragma unroll
            for (int v2 = 0; v2 < 8; ++v2)
                atomicAdd(&u.acc[dd[v2] * H_F + lane], vv[v2]);
        }
        __syncthreads();
        for (int k = 0; k < 16; ++k) {
            int nl = wave * 16 + k;
            int gn = gbase + nl;
            if (gn < N) {
                float v = u.acc[nl * H_F + lane] * norm_in[gn] + bj;
                hacc = fmaf(v > 0.0f ? v : 0.0f, norm_out[gn] * wsum[gn], hacc);
            }
        }
    }

    hl[wave][lane] = hacc;
    __syncthreads();
    if (wave == 0)
        partials[(size_t)blockIdx.x * 64 + lane] =
            (hl[0][lane] + hl[1][lane]) + (hl[2][lane] + hl[3][lane]);
}

// ---------------- final: hsum (f64) -> out = hsum@W2/N + b2 ----------------
__global__ __launch_bounds__(256) void k_final(const float* __restrict__ partials,
                                               const float* __restrict__ W2,
                                               const float* __restrict__ b2,
                                               float* __restrict__ out, int nb, int N) {
    __shared__ double hs[4][64];
    const int sub = threadIdx.x >> 6;   // 0..3
    const int j   = threadIdx.x & 63;
    double s = 0.0;
    for (int p = sub; p < nb; p += 4)
        s += (double)partials[(size_t)p * 64 + j];
    hs[sub][j] = s;
    __syncthreads();
    if (threadIdx.x < C_F) {
        int c = threadIdx.x;
        double o = 0.0;
        for (int k = 0; k < 64; ++k) {
            double hk = hs[0][k] + hs[1][k] + hs[2][k] + hs[3][k];
            o += hk * (double)W2[k * C_F + c];
        }
        out[c] = (float)(o / (double)N + (double)b2[c]);
    }
}

extern "C" void kernel_launch(void* const* d_in, const int* in_sizes, int n_in,
                              void* d_out, int out_size, void* d_ws, size_t ws_size,
                              hipStream_t stream) {
    const float* in_feat = (const float*)d_in[0];
    const int*   src     = (const int*)d_in[1];
    const int*   dst     = (const int*)d_in[2];
    const float* W1      = (const float*)d_in[3];
    const float* b1      = (const float*)d_in[4];
    const float* W2      = (const float*)d_in[5];
    const float* b2      = (const float*)d_in[6];
    float* out = (float*)d_out;

    const int N = in_sizes[0] / IN_F;           // 100000
    const int E = in_sizes[1];                  // 1600000
    const int nb = (N + BUCKET - 1) / BUCKET;   // 1563 (<= MAXB)

    // ---- workspace layout (4B units) ----
    unsigned int* binned = (unsigned int*)d_ws;          // E
    int*   degi_out  = (int*)(binned + E);               // N
    int*   degi_in   = degi_out + N;                     // N
    float* wsum      = (float*)(degi_in + N);            // N (zeroed with degrees)
    float* norm_out  = wsum + N;                         // N
    float* norm_in   = norm_out + N;                     // N
    int*   bucketCnt = (int*)(norm_in + N);              // MAXB
    int*   bucketBase= bucketCnt + MAXB;                 // MAXB+1
    int*   gCursor   = bucketBase + MAXB + 1;            // MAXB (+3 pad)
    __half* X1h      = (__half*)(gCursor + MAXB + 3);    // 64N halves
    float* partials  = (float*)(X1h + 64 * (size_t)N);   // nb*64

    // degrees + wsum are read-before-write (contiguous 3N)
    hipMemsetAsync(degi_out, 0, 3 * (size_t)N * sizeof(int), stream);

    k_degrees<<<(E + 255) / 256, 256, 0, stream>>>(src, dst, degi_out, degi_in, E);
    k_norms  <<<(N + 255) / 256, 256, 0, stream>>>(degi_out, degi_in, norm_out, norm_in, N);

    k_bucketcnt <<<(nb + 3) / 4, 256, 0, stream>>>(degi_in, bucketCnt, N, nb);
    k_bucketscan<<<1, 1024, 0, stream>>>(bucketCnt, bucketBase, gCursor, nb, E);

    k_bin<<<(E + EPB - 1) / EPB, 256, 0, stream>>>(src, dst, norm_in, wsum, gCursor,
                                                   binned, E, nb);

    k_gemm1<<<(N + 63) / 64, 256, 0, stream>>>(in_feat, W1, norm_out, X1h, N);

    k_agg<<<nb, 256, 0, stream>>>(X1h, binned, bucketBase, norm_in, norm_out,
                                  wsum, b1, partials, N);

    k_final<<<1, 256, 0, stream>>>(partials, W2, b2, out, nb, N);
}

// Round 8
// 313.319 us; speedup vs baseline: 3.2649x; 1.3954x over previous
//
#include <hip/hip_runtime.h>
#include <hip/hip_fp16.h>

#define IN_F 128
#define H_F 64
#define C_F 16
#define BUCKET 64           // nodes per bucket
#define BSH 6               // log2(BUCKET)
#define MAXB 2048           // hist/scan capacity (>= nBuckets = ceil(N/64))
#define EPB 8192            // edges per binning block
#define CAP 2048            // staged codes per k_agg block

// ---------------- fused bucket histograms (src + dst), no per-node atomics ----------
__global__ __launch_bounds__(256) void k_bhist(const int* __restrict__ src,
                                               const int* __restrict__ dst,
                                               int* __restrict__ cntS,
                                               int* __restrict__ cntD, int E, int nb) {
    __shared__ int hs[MAXB];
    __shared__ int hd[MAXB];
    const int tid = threadIdx.x;
    for (int i = tid; i < MAXB; i += 256) { hs[i] = 0; hd[i] = 0; }
    __syncthreads();
    const int start = blockIdx.x * EPB;
    for (int k = 0; k < EPB / 256; ++k) {
        int e = start + (k << 8) + tid;
        if (e < E) {
            atomicAdd(&hs[src[e] >> BSH], 1);
            atomicAdd(&hd[dst[e] >> BSH], 1);
        }
    }
    __syncthreads();
    for (int b = tid; b < nb; b += 256) {
        int s = hs[b], d = hd[b];
        if (s) atomicAdd(&cntS[b], s);
        if (d) atomicAdd(&cntD[b], d);
    }
}

// ---------------- exclusive scan of bucket counts (single block, 2 elems/thread) ------
__global__ __launch_bounds__(1024) void k_bucketscan(const int* __restrict__ bucketCnt,
                                                     int* __restrict__ bucketBase,
                                                     int* __restrict__ gCursor, int nb, int E) {
    __shared__ int s[1024];
    int t = threadIdx.x;
    int i0 = 2 * t, i1 = 2 * t + 1;
    int v0 = (i0 < nb) ? bucketCnt[i0] : 0;
    int v1 = (i1 < nb) ? bucketCnt[i1] : 0;
    int pair = v0 + v1;
    s[t] = pair;
    __syncthreads();
    for (int off = 1; off < 1024; off <<= 1) {
        int x = (t >= off) ? s[t - off] : 0;
        __syncthreads();
        s[t] += x;
        __syncthreads();
    }
    int excl = s[t] - pair;
    if (i0 < nb) { bucketBase[i0] = excl;      gCursor[i0] = excl; }
    if (i1 < nb) { bucketBase[i1] = excl + v0; gCursor[i1] = excl + v0; }
    if (t == 0) bucketBase[nb] = E;
}

// ---------------- generic bucket binning: code = (klocal<<17) | payload ----------------
__global__ __launch_bounds__(256) void k_bin(const int* __restrict__ key,
                                             const int* __restrict__ pay,
                                             int* __restrict__ gCursor,
                                             unsigned int* __restrict__ binned,
                                             int E, int nb) {
    __shared__ int hist[MAXB];
    __shared__ int base[MAXB];
    __shared__ int cur[MAXB];
    const int tid = threadIdx.x;
    const int start = blockIdx.x * EPB;
    for (int i = tid; i < MAXB; i += 256) { hist[i] = 0; cur[i] = 0; }
    __syncthreads();
    for (int k = 0; k < EPB / 256; ++k) {
        int e = start + (k << 8) + tid;
        if (e < E) atomicAdd(&hist[key[e] >> BSH], 1);
    }
    __syncthreads();
    for (int b = tid; b < nb; b += 256)
        if (hist[b]) base[b] = atomicAdd(&gCursor[b], hist[b]);
    __syncthreads();
    for (int k = 0; k < EPB / 256; ++k) {
        int e = start + (k << 8) + tid;
        if (e < E) {
            int kv = key[e];
            int b = kv >> BSH;
            int p = base[b] + atomicAdd(&cur[b], 1);
            binned[p] = ((unsigned)(kv & (BUCKET - 1)) << 17) | (unsigned)pay[e];
        }
    }
}

// ---------------- norm_in from binnedD (per dst-bucket 64-bin histogram) ----------------
__global__ __launch_bounds__(256) void k_normin(const unsigned int* __restrict__ binnedD,
                                                const int* __restrict__ baseD,
                                                float* __restrict__ norm_in, int N) {
    __shared__ int hist[BUCKET];
    const int tid = threadIdx.x;
    if (tid < BUCKET) hist[tid] = 0;
    __syncthreads();
    const int b = blockIdx.x;
    const int s0 = baseD[b], s1 = baseD[b + 1];
    for (int i = s0 + tid; i < s1; i += 256)
        atomicAdd(&hist[binnedD[i] >> 17], 1);
    __syncthreads();
    if (tid < BUCKET) {
        int gn = b * BUCKET + tid;
        if (gn < N) norm_in[gn] = 1.0f / sqrtf((float)max(hist[tid], 1));
    }
}

// ---------------- wsum + norm_out from binnedS (per src-bucket) ----------------
// wsum[s] = sum over edges(src=s) of norm_in[dst]; deg_out = count.
__global__ __launch_bounds__(256) void k_wsum(const unsigned int* __restrict__ binnedS,
                                              const int* __restrict__ baseS,
                                              const float* __restrict__ norm_in,
                                              float* __restrict__ wsum,
                                              float* __restrict__ norm_out, int N) {
    __shared__ float wloc[BUCKET];
    __shared__ int hist[BUCKET];
    const int tid = threadIdx.x;
    if (tid < BUCKET) { wloc[tid] = 0.0f; hist[tid] = 0; }
    __syncthreads();
    const int b = blockIdx.x;
    const int s0 = baseS[b], s1 = baseS[b + 1];
    for (int i = s0 + tid; i < s1; i += 256) {
        unsigned c = binnedS[i];
        int sl = (int)(c >> 17);
        float ni = norm_in[c & 0x1FFFFu];
        atomicAdd(&hist[sl], 1);
        atomicAdd(&wloc[sl], ni);
    }
    __syncthreads();
    if (tid < BUCKET) {
        int gn = b * BUCKET + tid;
        if (gn < N) {
            norm_out[gn] = 1.0f / sqrtf((float)max(hist[tid], 1));
            wsum[gn] = wloc[tid];
        }
    }
}

// ---------------- layer 1 GEMM: X1h = fp16((in_feat @ W1) * norm_out), [N,64] ----------
__global__ __launch_bounds__(256) void k_gemm1(const float* __restrict__ in_feat,
                                               const float* __restrict__ W1,
                                               const float* __restrict__ norm_out,
                                               __half* __restrict__ X1h, int N) {
    __shared__ float Wl[IN_F][H_F];       // 32 KB
    __shared__ float Al[64][IN_F + 4];    // 33 KB
    const int t = threadIdx.x;
    const int base = blockIdx.x * 64;

    for (int i = t; i < IN_F * H_F / 4; i += 256)
        ((float4*)&Wl[0][0])[i] = ((const float4*)W1)[i];
    for (int i = t; i < 64 * IN_F / 4; i += 256) {
        int n = i >> 5;
        int k4 = i & 31;
        int gn = base + n;
        float4 v = make_float4(0.f, 0.f, 0.f, 0.f);
        if (gn < N) v = ((const float4*)(in_feat + (size_t)gn * IN_F))[k4];
        *(float4*)&Al[n][k4 * 4] = v;
    }
    __syncthreads();

    const int c4 = (t & 15) * 4;
    const int r4 = (t >> 4) * 4;
    float acc[4][4] = {};
#pragma unroll 4
    for (int k = 0; k < IN_F; k += 4) {
        float4 w0 = *(const float4*)&Wl[k + 0][c4];
        float4 w1 = *(const float4*)&Wl[k + 1][c4];
        float4 w2 = *(const float4*)&Wl[k + 2][c4];
        float4 w3 = *(const float4*)&Wl[k + 3][c4];
        const float* wp0 = (const float*)&w0;
        const float* wp1 = (const float*)&w1;
        const float* wp2 = (const float*)&w2;
        const float* wp3 = (const float*)&w3;
#pragma unroll
        for (int i = 0; i < 4; ++i) {
            float4 a = *(const float4*)&Al[r4 + i][k];
#pragma unroll
            for (int jj = 0; jj < 4; ++jj)
                acc[i][jj] = fmaf(a.x, wp0[jj],
                             fmaf(a.y, wp1[jj],
                             fmaf(a.z, wp2[jj],
                             fmaf(a.w, wp3[jj], acc[i][jj]))));
        }
    }
#pragma unroll
    for (int i = 0; i < 4; ++i) {
        int n = base + r4 + i;
        if (n < N) {
            float no = norm_out[n];
            __half2 p0 = __floats2half2_rn(acc[i][0] * no, acc[i][1] * no);
            __half2 p1 = __floats2half2_rn(acc[i][2] * no, acc[i][3] * no);
            __half2* dp = (__half2*)&X1h[(size_t)n * H_F + c4];
            dp[0] = p0; dp[1] = p1;
        }
    }
}

// ---- fused aggregation: in-LDS counting sort by dlocal + REGISTER accumulation -------
// block = bucket (64 nodes); wave w owns nodes [w*16, w*16+16); lane = feature.
__global__ __launch_bounds__(256) void k_agg(const __half* __restrict__ X1h,
                                             const unsigned int* __restrict__ binned,
                                             const int* __restrict__ bucketBase,
                                             const float* __restrict__ norm_in,
                                             const float* __restrict__ norm_out,
                                             const float* __restrict__ wsum,
                                             const float* __restrict__ b1,
                                             float* __restrict__ partials, int N) {
    __shared__ union {
        struct { unsigned cds[CAP]; unsigned cds2[CAP]; } f;   // 16 KB
        float acc[BUCKET * H_F];                               // 16 KB (fallback)
    } u;
    __shared__ int hist[BUCKET];
    __shared__ int cur[BUCKET];
    __shared__ int loff[BUCKET + 1];
    __shared__ float hl[4][64];
    const int tid = threadIdx.x, lane = tid & 63, wave = tid >> 6;
    const int base = bucketBase[blockIdx.x];
    const int cnt  = bucketBase[blockIdx.x + 1] - base;
    const int gbase = blockIdx.x * BUCKET;
    const float bj = b1[lane];
    float hacc = 0.0f;

    if (cnt <= CAP) {
        // ---------- fast path ----------
        if (tid < BUCKET) hist[tid] = 0;
        __syncthreads();
        for (int i = tid; i < cnt; i += 256) {
            unsigned c = binned[base + i];
            u.f.cds[i] = c;
            atomicAdd(&hist[c >> 17], 1);
        }
        __syncthreads();
        if (wave == 0) {
            int v = hist[lane];
            int inc = v;
#pragma unroll
            for (int off = 1; off < 64; off <<= 1) {
                int t2 = __shfl_up(inc, off);
                if (lane >= off) inc += t2;
            }
            loff[lane + 1] = inc;
            cur[lane] = inc - v;          // exclusive prefix
            if (lane == 0) loff[0] = 0;
        }
        __syncthreads();
        for (int i = tid; i < cnt; i += 256) {
            unsigned c = u.f.cds[i];
            int p = atomicAdd(&cur[c >> 17], 1);
            u.f.cds2[p] = c;
        }
        __syncthreads();
        for (int k = 0; k < 16; ++k) {
            int nl = wave * 16 + k;
            int gn = gbase + nl;
            if (gn >= N) break;
            int s0 = loff[nl], s1 = loff[nl + 1];
            float acc = 0.0f;
            int e = s0;
            for (; e + 3 < s1; e += 4) {
                int sa = (int)(u.f.cds2[e]     & 0x1FFFFu);
                int sb = (int)(u.f.cds2[e + 1] & 0x1FFFFu);
                int sc = (int)(u.f.cds2[e + 2] & 0x1FFFFu);
                int sd = (int)(u.f.cds2[e + 3] & 0x1FFFFu);
                float a0 = __half2float(X1h[(size_t)sa * H_F + lane]);
                float a1 = __half2float(X1h[(size_t)sb * H_F + lane]);
                float a2 = __half2float(X1h[(size_t)sc * H_F + lane]);
                float a3 = __half2float(X1h[(size_t)sd * H_F + lane]);
                acc += (a0 + a1) + (a2 + a3);
            }
            for (; e < s1; ++e)
                acc += __half2float(X1h[(size_t)(u.f.cds2[e] & 0x1FFFFu) * H_F + lane]);
            float v = acc * norm_in[gn] + bj;
            hacc = fmaf(v > 0.0f ? v : 0.0f, norm_out[gn] * wsum[gn], hacc);
        }
    } else {
        // ---------- fallback (cnt > CAP; statistically never for this graph) ----------
        for (int i = tid; i < BUCKET * H_F / 4; i += 256)
            ((float4*)u.acc)[i] = make_float4(0.f, 0.f, 0.f, 0.f);
        __syncthreads();
        for (int e0 = wave * 8; e0 < cnt; e0 += 32) {
            unsigned cc[8];
            float vv[8];
            int dd[8];
#pragma unroll
            for (int v2 = 0; v2 < 8; ++v2) {
                int e = e0 + v2;
                cc[v2] = (e < cnt) ? binned[base + e] : 0u;
            }
#pragma unroll
            for (int v2 = 0; v2 < 8; ++v2) {
                int e = e0 + v2;
                int s = (int)(cc[v2] & 0x1FFFFu);
                dd[v2] = (int)(cc[v2] >> 17);
                vv[v2] = (e < cnt) ? __half2float(X1h[(size_t)s * H_F + lane]) : 0.0f;
            }
#pragma unroll
            for (int v2 = 0; v2 < 8; ++v2)
                atomicAdd(&u.acc[dd[v2] * H_F + lane], vv[v2]);
        }
        __syncthreads();
        for (int k = 0; k < 16; ++k) {
            int nl = wave * 16 + k;
            int gn = gbase + nl;
            if (gn < N) {
                float v = u.acc[nl * H_F + lane] * norm_in[gn] + bj;
                hacc = fmaf(v > 0.0f ? v : 0.0f, norm_out[gn] * wsum[gn], hacc);
            }
        }
    }

    hl[wave][lane] = hacc;
    __syncthreads();
    if (wave == 0)
        partials[(size_t)blockIdx.x * 64 + lane] =
            (hl[0][lane] + hl[1][lane]) + (hl[2][lane] + hl[3][lane]);
}

// ---------------- final: hsum (f64) -> out = hsum@W2/N + b2 ----------------
__global__ __launch_bounds__(256) void k_final(const float* __restrict__ partials,
                                               const float* __restrict__ W2,
                                               const float* __restrict__ b2,
                                               float* __restrict__ out, int nb, int N) {
    __shared__ double hs[4][64];
    const int sub = threadIdx.x >> 6;   // 0..3
    const int j   = threadIdx.x & 63;
    double s = 0.0;
    for (int p = sub; p < nb; p += 4)
        s += (double)partials[(size_t)p * 64 + j];
    hs[sub][j] = s;
    __syncthreads();
    if (threadIdx.x < C_F) {
        int c = threadIdx.x;
        double o = 0.0;
        for (int k = 0; k < 64; ++k) {
            double hk = hs[0][k] + hs[1][k] + hs[2][k] + hs[3][k];
            o += hk * (double)W2[k * C_F + c];
        }
        out[c] = (float)(o / (double)N + (double)b2[c]);
    }
}

extern "C" void kernel_launch(void* const* d_in, const int* in_sizes, int n_in,
                              void* d_out, int out_size, void* d_ws, size_t ws_size,
                              hipStream_t stream) {
    const float* in_feat = (const float*)d_in[0];
    const int*   src     = (const int*)d_in[1];
    const int*   dst     = (const int*)d_in[2];
    const float* W1      = (const float*)d_in[3];
    const float* b1      = (const float*)d_in[4];
    const float* W2      = (const float*)d_in[5];
    const float* b2      = (const float*)d_in[6];
    float* out = (float*)d_out;

    const int N = in_sizes[0] / IN_F;           // 100000
    const int E = in_sizes[1];                  // 1600000
    const int nb = (N + BUCKET - 1) / BUCKET;   // 1563 (<= MAXB)
    const int nBin = (E + EPB - 1) / EPB;       // 196

    // ---- workspace layout (4B units) ----
    unsigned int* binnedD = (unsigned int*)d_ws;         // E
    unsigned int* binnedS = binnedD + E;                 // E
    int*   cntD   = (int*)(binnedS + E);                 // MAXB  \ zeroed
    int*   cntS   = cntD + MAXB;                         // MAXB  /
    int*   baseD  = cntS + MAXB;                         // MAXB+1
    int*   curD   = baseD + MAXB + 1;                    // MAXB
    int*   baseS  = curD + MAXB;                         // MAXB+1
    int*   curS   = baseS + MAXB + 1;                    // MAXB
    float* norm_in  = (float*)(curS + MAXB);             // N
    float* norm_out = norm_in + N;                       // N
    float* wsum     = norm_out + N;                      // N
    __half* X1h     = (__half*)(wsum + N);               // 64N halves
    float* partials = (float*)(X1h + 64 * (size_t)N);    // nb*64

    // only the bucket-count accumulators are read-before-write
    hipMemsetAsync(cntD, 0, 2 * MAXB * sizeof(int), stream);

    k_bhist<<<nBin, 256, 0, stream>>>(src, dst, cntS, cntD, E, nb);

    k_bucketscan<<<1, 1024, 0, stream>>>(cntD, baseD, curD, nb, E);
    k_bucketscan<<<1, 1024, 0, stream>>>(cntS, baseS, curS, nb, E);

    k_bin<<<nBin, 256, 0, stream>>>(dst, src, curD, binnedD, E, nb);   // by dst
    k_bin<<<nBin, 256, 0, stream>>>(src, dst, curS, binnedS, E, nb);   // by src

    k_normin<<<nb, 256, 0, stream>>>(binnedD, baseD, norm_in, N);
    k_wsum  <<<nb, 256, 0, stream>>>(binnedS, baseS, norm_in, wsum, norm_out, N);

    k_gemm1<<<(N + 63) / 64, 256, 0, stream>>>(in_feat, W1, norm_out, X1h, N);

    k_agg<<<nb, 256, 0, stream>>>(X1h, binnedD, baseD, norm_in, norm_out,
                                  wsum, b1, partials, N);

    k_final<<<1, 256, 0, stream>>>(partials, W2, b2, out, nb, N);
}

// Round 9
// 225.789 us; speedup vs baseline: 4.5306x; 1.3877x over previous
//
#include <hip/hip_runtime.h>
#include <hip/hip_fp16.h>

#define IN_F 128
#define H_F 64
#define C_F 16
#define BUCKET 64           // nodes per bucket
#define BSH 6               // log2(BUCKET)
#define MAXB 2048           // hist/scan capacity (>= nBuckets = ceil(N/64))
#define EPB 8192            // edges per binning block
#define CAP 2048            // staged codes per k_agg block
#define NRED 64             // stage-1 reduction blocks

// ---------------- fused bucket histograms (src + dst), no per-node atomics ----------
__global__ __launch_bounds__(256) void k_bhist(const int* __restrict__ src,
                                               const int* __restrict__ dst,
                                               int* __restrict__ cntS,
                                               int* __restrict__ cntD, int E, int nb) {
    __shared__ int hs[MAXB];
    __shared__ int hd[MAXB];
    const int tid = threadIdx.x;
    for (int i = tid; i < MAXB; i += 256) { hs[i] = 0; hd[i] = 0; }
    __syncthreads();
    const int start = blockIdx.x * EPB;
    for (int k = 0; k < EPB / 256; ++k) {
        int e = start + (k << 8) + tid;
        if (e < E) {
            atomicAdd(&hs[src[e] >> BSH], 1);
            atomicAdd(&hd[dst[e] >> BSH], 1);
        }
    }
    __syncthreads();
    for (int b = tid; b < nb; b += 256) {
        int s = hs[b], d = hd[b];
        if (s) atomicAdd(&cntS[b], s);
        if (d) atomicAdd(&cntD[b], d);
    }
}

// ---------------- exclusive scan of bucket counts (single block, 2 elems/thread) ------
__global__ __launch_bounds__(1024) void k_bucketscan(const int* __restrict__ bucketCnt,
                                                     int* __restrict__ bucketBase,
                                                     int* __restrict__ gCursor, int nb, int E) {
    __shared__ int s[1024];
    int t = threadIdx.x;
    int i0 = 2 * t, i1 = 2 * t + 1;
    int v0 = (i0 < nb) ? bucketCnt[i0] : 0;
    int v1 = (i1 < nb) ? bucketCnt[i1] : 0;
    int pair = v0 + v1;
    s[t] = pair;
    __syncthreads();
    for (int off = 1; off < 1024; off <<= 1) {
        int x = (t >= off) ? s[t - off] : 0;
        __syncthreads();
        s[t] += x;
        __syncthreads();
    }
    int excl = s[t] - pair;
    if (i0 < nb) { bucketBase[i0] = excl;      gCursor[i0] = excl; }
    if (i1 < nb) { bucketBase[i1] = excl + v0; gCursor[i1] = excl + v0; }
    if (t == 0) bucketBase[nb] = E;
}

// ---------------- generic bucket binning: code = (klocal<<17) | payload ----------------
__global__ __launch_bounds__(256) void k_bin(const int* __restrict__ key,
                                             const int* __restrict__ pay,
                                             int* __restrict__ gCursor,
                                             unsigned int* __restrict__ binned,
                                             int E, int nb) {
    __shared__ int hist[MAXB];
    __shared__ int base[MAXB];
    __shared__ int cur[MAXB];
    const int tid = threadIdx.x;
    const int start = blockIdx.x * EPB;
    for (int i = tid; i < MAXB; i += 256) { hist[i] = 0; cur[i] = 0; }
    __syncthreads();
    for (int k = 0; k < EPB / 256; ++k) {
        int e = start + (k << 8) + tid;
        if (e < E) atomicAdd(&hist[key[e] >> BSH], 1);
    }
    __syncthreads();
    for (int b = tid; b < nb; b += 256)
        if (hist[b]) base[b] = atomicAdd(&gCursor[b], hist[b]);
    __syncthreads();
    for (int k = 0; k < EPB / 256; ++k) {
        int e = start + (k << 8) + tid;
        if (e < E) {
            int kv = key[e];
            int b = kv >> BSH;
            int p = base[b] + atomicAdd(&cur[b], 1);
            binned[p] = ((unsigned)(kv & (BUCKET - 1)) << 17) | (unsigned)pay[e];
        }
    }
}

// ---------------- norm_in from binnedD (per dst-bucket 64-bin histogram) ----------------
__global__ __launch_bounds__(256) void k_normin(const unsigned int* __restrict__ binnedD,
                                                const int* __restrict__ baseD,
                                                float* __restrict__ norm_in, int N) {
    __shared__ int hist[BUCKET];
    const int tid = threadIdx.x;
    if (tid < BUCKET) hist[tid] = 0;
    __syncthreads();
    const int b = blockIdx.x;
    const int s0 = baseD[b], s1 = baseD[b + 1];
    for (int i = s0 + tid; i < s1; i += 256)
        atomicAdd(&hist[binnedD[i] >> 17], 1);
    __syncthreads();
    if (tid < BUCKET) {
        int gn = b * BUCKET + tid;
        if (gn < N) norm_in[gn] = 1.0f / sqrtf((float)max(hist[tid], 1));
    }
}

// ---------------- wsum + norm_out from binnedS (per src-bucket) ----------------
__global__ __launch_bounds__(256) void k_wsum(const unsigned int* __restrict__ binnedS,
                                              const int* __restrict__ baseS,
                                              const float* __restrict__ norm_in,
                                              float* __restrict__ wsum,
                                              float* __restrict__ norm_out, int N) {
    __shared__ float wloc[BUCKET];
    __shared__ int hist[BUCKET];
    const int tid = threadIdx.x;
    if (tid < BUCKET) { wloc[tid] = 0.0f; hist[tid] = 0; }
    __syncthreads();
    const int b = blockIdx.x;
    const int s0 = baseS[b], s1 = baseS[b + 1];
    for (int i = s0 + tid; i < s1; i += 256) {
        unsigned c = binnedS[i];
        int sl = (int)(c >> 17);
        float ni = norm_in[c & 0x1FFFFu];
        atomicAdd(&hist[sl], 1);
        atomicAdd(&wloc[sl], ni);
    }
    __syncthreads();
    if (tid < BUCKET) {
        int gn = b * BUCKET + tid;
        if (gn < N) {
            norm_out[gn] = 1.0f / sqrtf((float)max(hist[tid], 1));
            wsum[gn] = wloc[tid];
        }
    }
}

// ---------------- layer 1 GEMM: X1h = fp16((in_feat @ W1) * norm_out), [N,64] ----------
__global__ __launch_bounds__(256) void k_gemm1(const float* __restrict__ in_feat,
                                               const float* __restrict__ W1,
                                               const float* __restrict__ norm_out,
                                               __half* __restrict__ X1h, int N) {
    __shared__ float Wl[IN_F][H_F];       // 32 KB
    __shared__ float Al[64][IN_F + 4];    // 33 KB
    const int t = threadIdx.x;
    const int base = blockIdx.x * 64;

    for (int i = t; i < IN_F * H_F / 4; i += 256)
        ((float4*)&Wl[0][0])[i] = ((const float4*)W1)[i];
    for (int i = t; i < 64 * IN_F / 4; i += 256) {
        int n = i >> 5;
        int k4 = i & 31;
        int gn = base + n;
        float4 v = make_float4(0.f, 0.f, 0.f, 0.f);
        if (gn < N) v = ((const float4*)(in_feat + (size_t)gn * IN_F))[k4];
        *(float4*)&Al[n][k4 * 4] = v;
    }
    __syncthreads();

    const int c4 = (t & 15) * 4;
    const int r4 = (t >> 4) * 4;
    float acc[4][4] = {};
#pragma unroll 4
    for (int k = 0; k < IN_F; k += 4) {
        float4 w0 = *(const float4*)&Wl[k + 0][c4];
        float4 w1 = *(const float4*)&Wl[k + 1][c4];
        float4 w2 = *(const float4*)&Wl[k + 2][c4];
        float4 w3 = *(const float4*)&Wl[k + 3][c4];
        const float* wp0 = (const float*)&w0;
        const float* wp1 = (const float*)&w1;
        const float* wp2 = (const float*)&w2;
        const float* wp3 = (const float*)&w3;
#pragma unroll
        for (int i = 0; i < 4; ++i) {
            float4 a = *(const float4*)&Al[r4 + i][k];
#pragma unroll
            for (int jj = 0; jj < 4; ++jj)
                acc[i][jj] = fmaf(a.x, wp0[jj],
                             fmaf(a.y, wp1[jj],
                             fmaf(a.z, wp2[jj],
                             fmaf(a.w, wp3[jj], acc[i][jj]))));
        }
    }
#pragma unroll
    for (int i = 0; i < 4; ++i) {
        int n = base + r4 + i;
        if (n < N) {
            float no = norm_out[n];
            __half2 p0 = __floats2half2_rn(acc[i][0] * no, acc[i][1] * no);
            __half2 p1 = __floats2half2_rn(acc[i][2] * no, acc[i][3] * no);
            __half2* dp = (__half2*)&X1h[(size_t)n * H_F + c4];
            dp[0] = p0; dp[1] = p1;
        }
    }
}

// ---- fused aggregation: in-LDS counting sort by dlocal + REGISTER accumulation -------
__global__ __launch_bounds__(256) void k_agg(const __half* __restrict__ X1h,
                                             const unsigned int* __restrict__ binned,
                                             const int* __restrict__ bucketBase,
                                             const float* __restrict__ norm_in,
                                             const float* __restrict__ norm_out,
                                             const float* __restrict__ wsum,
                                             const float* __restrict__ b1,
                                             float* __restrict__ partials, int N) {
    __shared__ union {
        struct { unsigned cds[CAP]; unsigned cds2[CAP]; } f;   // 16 KB
        float acc[BUCKET * H_F];                               // 16 KB (fallback)
    } u;
    __shared__ int hist[BUCKET];
    __shared__ int cur[BUCKET];
    __shared__ int loff[BUCKET + 1];
    __shared__ float hl[4][64];
    const int tid = threadIdx.x, lane = tid & 63, wave = tid >> 6;
    const int base = bucketBase[blockIdx.x];
    const int cnt  = bucketBase[blockIdx.x + 1] - base;
    const int gbase = blockIdx.x * BUCKET;
    const float bj = b1[lane];
    float hacc = 0.0f;

    if (cnt <= CAP) {
        // ---------- fast path ----------
        if (tid < BUCKET) hist[tid] = 0;
        __syncthreads();
        for (int i = tid; i < cnt; i += 256) {
            unsigned c = binned[base + i];
            u.f.cds[i] = c;
            atomicAdd(&hist[c >> 17], 1);
        }
        __syncthreads();
        if (wave == 0) {
            int v = hist[lane];
            int inc = v;
#pragma unroll
            for (int off = 1; off < 64; off <<= 1) {
                int t2 = __shfl_up(inc, off);
                if (lane >= off) inc += t2;
            }
            loff[lane + 1] = inc;
            cur[lane] = inc - v;          // exclusive prefix
            if (lane == 0) loff[0] = 0;
        }
        __syncthreads();
        for (int i = tid; i < cnt; i += 256) {
            unsigned c = u.f.cds[i];
            int p = atomicAdd(&cur[c >> 17], 1);
            u.f.cds2[p] = c;
        }
        __syncthreads();
        for (int k = 0; k < 16; ++k) {
            int nl = wave * 16 + k;
            int gn = gbase + nl;
            if (gn >= N) break;
            int s0 = loff[nl], s1 = loff[nl + 1];
            float acc = 0.0f;
            int e = s0;
            for (; e + 3 < s1; e += 4) {
                int sa = (int)(u.f.cds2[e]     & 0x1FFFFu);
                int sb = (int)(u.f.cds2[e + 1] & 0x1FFFFu);
                int sc = (int)(u.f.cds2[e + 2] & 0x1FFFFu);
                int sd = (int)(u.f.cds2[e + 3] & 0x1FFFFu);
                float a0 = __half2float(X1h[(size_t)sa * H_F + lane]);
                float a1 = __half2float(X1h[(size_t)sb * H_F + lane]);
                float a2 = __half2float(X1h[(size_t)sc * H_F + lane]);
                float a3 = __half2float(X1h[(size_t)sd * H_F + lane]);
                acc += (a0 + a1) + (a2 + a3);
            }
            for (; e < s1; ++e)
                acc += __half2float(X1h[(size_t)(u.f.cds2[e] & 0x1FFFFu) * H_F + lane]);
            float v = acc * norm_in[gn] + bj;
            hacc = fmaf(v > 0.0f ? v : 0.0f, norm_out[gn] * wsum[gn], hacc);
        }
    } else {
        // ---------- fallback (cnt > CAP; statistically never for this graph) ----------
        for (int i = tid; i < BUCKET * H_F / 4; i += 256)
            ((float4*)u.acc)[i] = make_float4(0.f, 0.f, 0.f, 0.f);
        __syncthreads();
        for (int e0 = wave * 8; e0 < cnt; e0 += 32) {
            unsigned cc[8];
            float vv[8];
            int dd[8];
#pragma unroll
            for (int v2 = 0; v2 < 8; ++v2) {
                int e = e0 + v2;
                cc[v2] = (e < cnt) ? binned[base + e] : 0u;
            }
#pragma unroll
            for (int v2 = 0; v2 < 8; ++v2) {
                int e = e0 + v2;
                int s = (int)(cc[v2] & 0x1FFFFu);
                dd[v2] = (int)(cc[v2] >> 17);
                vv[v2] = (e < cnt) ? __half2float(X1h[(size_t)s * H_F + lane]) : 0.0f;
            }
#pragma unroll
            for (int v2 = 0; v2 < 8; ++v2)
                atomicAdd(&u.acc[dd[v2] * H_F + lane], vv[v2]);
        }
        __syncthreads();
        for (int k = 0; k < 16; ++k) {
            int nl = wave * 16 + k;
            int gn = gbase + nl;
            if (gn < N) {
                float v = u.acc[nl * H_F + lane] * norm_in[gn] + bj;
                hacc = fmaf(v > 0.0f ? v : 0.0f, norm_out[gn] * wsum[gn], hacc);
            }
        }
    }

    hl[wave][lane] = hacc;
    __syncthreads();
    if (wave == 0)
        partials[(size_t)blockIdx.x * 64 + lane] =
            (hl[0][lane] + hl[1][lane]) + (hl[2][lane] + hl[3][lane]);
}

// ---------------- stage-1 reduction: partials[nb][64] -> red[NRED][64] (f64) ----------
__global__ __launch_bounds__(256) void k_red(const float* __restrict__ partials,
                                             double* __restrict__ red, int nb) {
    const int lane = threadIdx.x & 63, wave = threadIdx.x >> 6;
    const int rpb = (nb + NRED - 1) / NRED;
    const int r0 = blockIdx.x * rpb;
    int r1 = r0 + rpb; if (r1 > nb) r1 = nb;
    double s = 0.0;
    for (int r = r0 + wave; r < r1; r += 4)
        s += (double)partials[(size_t)r * 64 + lane];
    __shared__ double sd[4][64];
    sd[wave][lane] = s;
    __syncthreads();
    if (wave == 0)
        red[(size_t)blockIdx.x * 64 + lane] =
            (sd[0][lane] + sd[1][lane]) + (sd[2][lane] + sd[3][lane]);
}

// ---------------- final: red (f64) -> out = hsum@W2/N + b2 ----------------
__global__ __launch_bounds__(256) void k_final(const double* __restrict__ red,
                                               const float* __restrict__ W2,
                                               const float* __restrict__ b2,
                                               float* __restrict__ out, int N) {
    __shared__ double hs[4][64];
    const int sub = threadIdx.x >> 6;   // 0..3
    const int j   = threadIdx.x & 63;
    double s = 0.0;
    for (int p = sub; p < NRED; p += 4)
        s += red[(size_t)p * 64 + j];
    hs[sub][j] = s;
    __syncthreads();
    if (threadIdx.x < C_F) {
        int c = threadIdx.x;
        double o = 0.0;
        for (int k = 0; k < 64; ++k) {
            double hk = hs[0][k] + hs[1][k] + hs[2][k] + hs[3][k];
            o += hk * (double)W2[k * C_F + c];
        }
        out[c] = (float)(o / (double)N + (double)b2[c]);
    }
}

extern "C" void kernel_launch(void* const* d_in, const int* in_sizes, int n_in,
                              void* d_out, int out_size, void* d_ws, size_t ws_size,
                              hipStream_t stream) {
    const float* in_feat = (const float*)d_in[0];
    const int*   src     = (const int*)d_in[1];
    const int*   dst     = (const int*)d_in[2];
    const float* W1      = (const float*)d_in[3];
    const float* b1      = (const float*)d_in[4];
    const float* W2      = (const float*)d_in[5];
    const float* b2      = (const float*)d_in[6];
    float* out = (float*)d_out;

    const int N = in_sizes[0] / IN_F;           // 100000
    const int E = in_sizes[1];                  // 1600000
    const int nb = (N + BUCKET - 1) / BUCKET;   // 1563 (<= MAXB)
    const int nBin = (E + EPB - 1) / EPB;       // 196

    // ---- workspace layout (4B units) ----
    unsigned int* binnedD = (unsigned int*)d_ws;         // E
    unsigned int* binnedS = binnedD + E;                 // E
    int*   cntD   = (int*)(binnedS + E);                 // MAXB  \ zeroed
    int*   cntS   = cntD + MAXB;                         // MAXB  /
    int*   baseD  = cntS + MAXB;                         // MAXB+1
    int*   curD   = baseD + MAXB + 1;                    // MAXB
    int*   baseS  = curD + MAXB;                         // MAXB+1
    int*   curS   = baseS + MAXB + 1;                    // MAXB
    float* norm_in  = (float*)(curS + MAXB);             // N
    float* norm_out = norm_in + N;                       // N
    float* wsum     = norm_out + N;                      // N
    __half* X1h     = (__half*)(wsum + N);               // 64N halves
    float* partials = (float*)(X1h + 64 * (size_t)N);    // nb*64
    double* red     = (double*)(partials + (size_t)nb * 64);  // NRED*64 f64

    // only the bucket-count accumulators are read-before-write
    hipMemsetAsync(cntD, 0, 2 * MAXB * sizeof(int), stream);

    k_bhist<<<nBin, 256, 0, stream>>>(src, dst, cntS, cntD, E, nb);

    k_bucketscan<<<1, 1024, 0, stream>>>(cntD, baseD, curD, nb, E);
    k_bucketscan<<<1, 1024, 0, stream>>>(cntS, baseS, curS, nb, E);

    k_bin<<<nBin, 256, 0, stream>>>(dst, src, curD, binnedD, E, nb);   // by dst
    k_bin<<<nBin, 256, 0, stream>>>(src, dst, curS, binnedS, E, nb);   // by src

    k_normin<<<nb, 256, 0, stream>>>(binnedD, baseD, norm_in, N);
    k_wsum  <<<nb, 256, 0, stream>>>(binnedS, baseS, norm_in, wsum, norm_out, N);

    k_gemm1<<<(N + 63) / 64, 256, 0, stream>>>(in_feat, W1, norm_out, X1h, N);

    k_agg<<<nb, 256, 0, stream>>>(X1h, binnedD, baseD, norm_in, norm_out,
                                  wsum, b1, partials, N);

    k_red  <<<NRED, 256, 0, stream>>>(partials, red, nb);
    k_final<<<1, 256, 0, stream>>>(red, W2, b2, out, N);
}

// Round 10
// 203.289 us; speedup vs baseline: 5.0321x; 1.1107x over previous
//
#include <hip/hip_runtime.h>
#include <hip/hip_fp16.h>

#define IN_F 128
#define H_F 64
#define C_F 16
#define BUCKET 64           // nodes per bucket
#define BSH 6               // log2(BUCKET)
#define MAXB 2048           // hist/scan capacity (>= nBuckets = ceil(N/64))
#define EPB 8192            // edges per binning block
#define CAP 2048            // staged codes per k_agg block
#define NRED 64             // stage-1 reduction blocks

// ---------------- fused bucket histograms (src + dst), no per-node atomics ----------
__global__ __launch_bounds__(256) void k_bhist(const int* __restrict__ src,
                                               const int* __restrict__ dst,
                                               int* __restrict__ cntS,
                                               int* __restrict__ cntD, int E, int nb) {
    __shared__ int hs[MAXB];
    __shared__ int hd[MAXB];
    const int tid = threadIdx.x;
    for (int i = tid; i < MAXB; i += 256) { hs[i] = 0; hd[i] = 0; }
    __syncthreads();
    const int start = blockIdx.x * EPB;
    for (int k = 0; k < EPB / 256; ++k) {
        int e = start + (k << 8) + tid;
        if (e < E) {
            atomicAdd(&hs[src[e] >> BSH], 1);
            atomicAdd(&hd[dst[e] >> BSH], 1);
        }
    }
    __syncthreads();
    for (int b = tid; b < nb; b += 256) {
        int s = hs[b], d = hd[b];
        if (s) atomicAdd(&cntS[b], s);
        if (d) atomicAdd(&cntD[b], d);
    }
}

// ------------- exclusive scans of BOTH bucket-count arrays (single block) -------------
__global__ __launch_bounds__(1024) void k_bucketscan2(const int* __restrict__ cntD,
                                                      const int* __restrict__ cntS,
                                                      int* __restrict__ baseD,
                                                      int* __restrict__ curD,
                                                      int* __restrict__ baseS,
                                                      int* __restrict__ curS,
                                                      int nb, int E) {
    __shared__ int s[1024];
    const int t = threadIdx.x;
    for (int pass = 0; pass < 2; ++pass) {
        const int* cnt = pass ? cntS : cntD;
        int* base = pass ? baseS : baseD;
        int* cur  = pass ? curS  : curD;
        int i0 = 2 * t, i1 = 2 * t + 1;
        int v0 = (i0 < nb) ? cnt[i0] : 0;
        int v1 = (i1 < nb) ? cnt[i1] : 0;
        int pair = v0 + v1;
        s[t] = pair;
        __syncthreads();
        for (int off = 1; off < 1024; off <<= 1) {
            int x = (t >= off) ? s[t - off] : 0;
            __syncthreads();
            s[t] += x;
            __syncthreads();
        }
        int excl = s[t] - pair;
        if (i0 < nb) { base[i0] = excl;      cur[i0] = excl; }
        if (i1 < nb) { base[i1] = excl + v0; cur[i1] = excl + v0; }
        if (t == 0) base[nb] = E;
        __syncthreads();
    }
}

// ------------- fused dual binning: by dst (pay=src) AND by src (pay=dst) --------------
// code = (klocal << 17) | payload
__global__ __launch_bounds__(256) void k_bin2(const int* __restrict__ src,
                                              const int* __restrict__ dst,
                                              int* __restrict__ gCurD,
                                              int* __restrict__ gCurS,
                                              unsigned int* __restrict__ binnedD,
                                              unsigned int* __restrict__ binnedS,
                                              int E, int nb) {
    __shared__ int hd[MAXB], hs[MAXB];
    __shared__ int bd[MAXB], bs[MAXB];
    __shared__ int cd[MAXB], cs[MAXB];
    const int tid = threadIdx.x;
    const int start = blockIdx.x * EPB;
    for (int i = tid; i < MAXB; i += 256) { hd[i] = 0; hs[i] = 0; cd[i] = 0; cs[i] = 0; }
    __syncthreads();
    for (int k = 0; k < EPB / 256; ++k) {
        int e = start + (k << 8) + tid;
        if (e < E) {
            atomicAdd(&hd[dst[e] >> BSH], 1);
            atomicAdd(&hs[src[e] >> BSH], 1);
        }
    }
    __syncthreads();
    for (int b = tid; b < nb; b += 256) {
        if (hd[b]) bd[b] = atomicAdd(&gCurD[b], hd[b]);
        if (hs[b]) bs[b] = atomicAdd(&gCurS[b], hs[b]);
    }
    __syncthreads();
    for (int k = 0; k < EPB / 256; ++k) {
        int e = start + (k << 8) + tid;
        if (e < E) {
            int sv = src[e], dv = dst[e];
            int b1 = dv >> BSH;
            int p1 = bd[b1] + atomicAdd(&cd[b1], 1);
            binnedD[p1] = ((unsigned)(dv & (BUCKET - 1)) << 17) | (unsigned)sv;
            int b2 = sv >> BSH;
            int p2 = bs[b2] + atomicAdd(&cs[b2], 1);
            binnedS[p2] = ((unsigned)(sv & (BUCKET - 1)) << 17) | (unsigned)dv;
        }
    }
}

// ---------------- norm_in from binnedD (per dst-bucket 64-bin histogram) ----------------
__global__ __launch_bounds__(256) void k_normin(const unsigned int* __restrict__ binnedD,
                                                const int* __restrict__ baseD,
                                                float* __restrict__ norm_in, int N) {
    __shared__ int hist[BUCKET];
    const int tid = threadIdx.x;
    if (tid < BUCKET) hist[tid] = 0;
    __syncthreads();
    const int b = blockIdx.x;
    const int s0 = baseD[b], s1 = baseD[b + 1];
    for (int i = s0 + tid; i < s1; i += 256)
        atomicAdd(&hist[binnedD[i] >> 17], 1);
    __syncthreads();
    if (tid < BUCKET) {
        int gn = b * BUCKET + tid;
        if (gn < N) norm_in[gn] = 1.0f / sqrtf((float)max(hist[tid], 1));
    }
}

// ---------------- wsum + norm_out from binnedS (per src-bucket) ----------------
__global__ __launch_bounds__(256) void k_wsum(const unsigned int* __restrict__ binnedS,
                                              const int* __restrict__ baseS,
                                              const float* __restrict__ norm_in,
                                              float* __restrict__ wsum,
                                              float* __restrict__ norm_out, int N) {
    __shared__ float wloc[BUCKET];
    __shared__ int hist[BUCKET];
    const int tid = threadIdx.x;
    if (tid < BUCKET) { wloc[tid] = 0.0f; hist[tid] = 0; }
    __syncthreads();
    const int b = blockIdx.x;
    const int s0 = baseS[b], s1 = baseS[b + 1];
    for (int i = s0 + tid; i < s1; i += 256) {
        unsigned c = binnedS[i];
        int sl = (int)(c >> 17);
        float ni = norm_in[c & 0x1FFFFu];
        atomicAdd(&hist[sl], 1);
        atomicAdd(&wloc[sl], ni);
    }
    __syncthreads();
    if (tid < BUCKET) {
        int gn = b * BUCKET + tid;
        if (gn < N) {
            norm_out[gn] = 1.0f / sqrtf((float)max(hist[tid], 1));
            wsum[gn] = wloc[tid];
        }
    }
}

// ------- layer 1 GEMM: X1q = fp8_e4m3((in_feat @ W1) * norm_out), [N,64] bytes -------
__global__ __launch_bounds__(256) void k_gemm1(const float* __restrict__ in_feat,
                                               const float* __restrict__ W1,
                                               const float* __restrict__ norm_out,
                                               unsigned char* __restrict__ X1q, int N) {
    __shared__ float Wl[IN_F][H_F];       // 32 KB
    __shared__ float Al[64][IN_F + 4];    // 33 KB
    const int t = threadIdx.x;
    const int base = blockIdx.x * 64;

    for (int i = t; i < IN_F * H_F / 4; i += 256)
        ((float4*)&Wl[0][0])[i] = ((const float4*)W1)[i];
    for (int i = t; i < 64 * IN_F / 4; i += 256) {
        int n = i >> 5;
        int k4 = i & 31;
        int gn = base + n;
        float4 v = make_float4(0.f, 0.f, 0.f, 0.f);
        if (gn < N) v = ((const float4*)(in_feat + (size_t)gn * IN_F))[k4];
        *(float4*)&Al[n][k4 * 4] = v;
    }
    __syncthreads();

    const int c4 = (t & 15) * 4;
    const int r4 = (t >> 4) * 4;
    float acc[4][4] = {};
#pragma unroll 4
    for (int k = 0; k < IN_F; k += 4) {
        float4 w0 = *(const float4*)&Wl[k + 0][c4];
        float4 w1 = *(const float4*)&Wl[k + 1][c4];
        float4 w2 = *(const float4*)&Wl[k + 2][c4];
        float4 w3 = *(const float4*)&Wl[k + 3][c4];
        const float* wp0 = (const float*)&w0;
        const float* wp1 = (const float*)&w1;
        const float* wp2 = (const float*)&w2;
        const float* wp3 = (const float*)&w3;
#pragma unroll
        for (int i = 0; i < 4; ++i) {
            float4 a = *(const float4*)&Al[r4 + i][k];
#pragma unroll
            for (int jj = 0; jj < 4; ++jj)
                acc[i][jj] = fmaf(a.x, wp0[jj],
                             fmaf(a.y, wp1[jj],
                             fmaf(a.z, wp2[jj],
                             fmaf(a.w, wp3[jj], acc[i][jj]))));
        }
    }
#pragma unroll
    for (int i = 0; i < 4; ++i) {
        int n = base + r4 + i;
        if (n < N) {
            float no = norm_out[n];
            int pk = 0;
            pk = __builtin_amdgcn_cvt_pk_fp8_f32(acc[i][0] * no, acc[i][1] * no, pk, false);
            pk = __builtin_amdgcn_cvt_pk_fp8_f32(acc[i][2] * no, acc[i][3] * no, pk, true);
            *(int*)&X1q[(size_t)n * H_F + c4] = pk;
        }
    }
}

// ---- fused aggregation: in-LDS counting sort by dlocal + REGISTER fp8 accumulation ---
// block = bucket (64 nodes); wave w owns nodes [w*16, w*16+16); lane = feature.
__global__ __launch_bounds__(256) void k_agg(const unsigned char* __restrict__ X1q,
                                             const unsigned int* __restrict__ binned,
                                             const int* __restrict__ bucketBase,
                                             const float* __restrict__ norm_in,
                                             const float* __restrict__ norm_out,
                                             const float* __restrict__ wsum,
                                             const float* __restrict__ b1,
                                             float* __restrict__ partials, int N) {
    __shared__ union {
        struct { unsigned cds[CAP]; unsigned cds2[CAP]; } f;   // 16 KB
        float acc[BUCKET * H_F];                               // 16 KB (fallback)
    } u;
    __shared__ int hist[BUCKET];
    __shared__ int cur[BUCKET];
    __shared__ int loff[BUCKET + 1];
    __shared__ float hl[4][64];
    const int tid = threadIdx.x, lane = tid & 63, wave = tid >> 6;
    const int base = bucketBase[blockIdx.x];
    const int cnt  = bucketBase[blockIdx.x + 1] - base;
    const int gbase = blockIdx.x * BUCKET;
    const float bj = b1[lane];
    float hacc = 0.0f;

    if (cnt <= CAP) {
        // ---------- fast path ----------
        if (tid < BUCKET) hist[tid] = 0;
        __syncthreads();
        for (int i = tid; i < cnt; i += 256) {
            unsigned c = binned[base + i];
            u.f.cds[i] = c;
            atomicAdd(&hist[c >> 17], 1);
        }
        __syncthreads();
        if (wave == 0) {
            int v = hist[lane];
            int inc = v;
#pragma unroll
            for (int off = 1; off < 64; off <<= 1) {
                int t2 = __shfl_up(inc, off);
                if (lane >= off) inc += t2;
            }
            loff[lane + 1] = inc;
            cur[lane] = inc - v;          // exclusive prefix
            if (lane == 0) loff[0] = 0;
        }
        __syncthreads();
        for (int i = tid; i < cnt; i += 256) {
            unsigned c = u.f.cds[i];
            int p = atomicAdd(&cur[c >> 17], 1);
            u.f.cds2[p] = c;
        }
        __syncthreads();
        for (int k = 0; k < 16; ++k) {
            int nl = wave * 16 + k;
            int gn = gbase + nl;
            if (gn >= N) break;
            int s0 = loff[nl], s1 = loff[nl + 1];
            float acc = 0.0f;
            int e = s0;
            for (; e + 7 < s1; e += 8) {
                int ss[8]; unsigned qq[8];
#pragma unroll
                for (int v2 = 0; v2 < 8; ++v2)
                    ss[v2] = (int)(u.f.cds2[e + v2] & 0x1FFFFu);
#pragma unroll
                for (int v2 = 0; v2 < 8; ++v2)
                    qq[v2] = X1q[(size_t)ss[v2] * H_F + lane];
#pragma unroll
                for (int v2 = 0; v2 < 8; ++v2)
                    acc += __builtin_amdgcn_cvt_f32_fp8(qq[v2], 0);
            }
            for (; e < s1; ++e) {
                unsigned q = X1q[(size_t)(u.f.cds2[e] & 0x1FFFFu) * H_F + lane];
                acc += __builtin_amdgcn_cvt_f32_fp8(q, 0);
            }
            float v = acc * norm_in[gn] + bj;
            hacc = fmaf(v > 0.0f ? v : 0.0f, norm_out[gn] * wsum[gn], hacc);
        }
    } else {
        // ---------- fallback (cnt > CAP; statistically never for this graph) ----------
        for (int i = tid; i < BUCKET * H_F / 4; i += 256)
            ((float4*)u.acc)[i] = make_float4(0.f, 0.f, 0.f, 0.f);
        __syncthreads();
        for (int e0 = wave * 8; e0 < cnt; e0 += 32) {
            unsigned cc[8];
            float vv[8];
            int dd[8];
#pragma unroll
            for (int v2 = 0; v2 < 8; ++v2) {
                int e = e0 + v2;
                cc[v2] = (e < cnt) ? binned[base + e] : 0u;
            }
#pragma unroll
            for (int v2 = 0; v2 < 8; ++v2) {
                int e = e0 + v2;
                int s = (int)(cc[v2] & 0x1FFFFu);
                dd[v2] = (int)(cc[v2] >> 17);
                vv[v2] = (e < cnt)
                    ? __builtin_amdgcn_cvt_f32_fp8((unsigned)X1q[(size_t)s * H_F + lane], 0)
                    : 0.0f;
            }
#pragma unroll
            for (int v2 = 0; v2 < 8; ++v2)
                atomicAdd(&u.acc[dd[v2] * H_F + lane], vv[v2]);
        }
        __syncthreads();
        for (int k = 0; k < 16; ++k) {
            int nl = wave * 16 + k;
            int gn = gbase + nl;
            if (gn < N) {
                float v = u.acc[nl * H_F + lane] * norm_in[gn] + bj;
                hacc = fmaf(v > 0.0f ? v : 0.0f, norm_out[gn] * wsum[gn], hacc);
            }
        }
    }

    hl[wave][lane] = hacc;
    __syncthreads();
    if (wave == 0)
        partials[(size_t)blockIdx.x * 64 + lane] =
            (hl[0][lane] + hl[1][lane]) + (hl[2][lane] + hl[3][lane]);
}

// ---------------- stage-1 reduction: partials[nb][64] -> red[NRED][64] (f64) ----------
__global__ __launch_bounds__(256) void k_red(const float* __restrict__ partials,
                                             double* __restrict__ red, int nb) {
    const int lane = threadIdx.x & 63, wave = threadIdx.x >> 6;
    const int rpb = (nb + NRED - 1) / NRED;
    const int r0 = blockIdx.x * rpb;
    int r1 = r0 + rpb; if (r1 > nb) r1 = nb;
    double s = 0.0;
    for (int r = r0 + wave; r < r1; r += 4)
        s += (double)partials[(size_t)r * 64 + lane];
    __shared__ double sd[4][64];
    sd[wave][lane] = s;
    __syncthreads();
    if (wave == 0)
        red[(size_t)blockIdx.x * 64 + lane] =
            (sd[0][lane] + sd[1][lane]) + (sd[2][lane] + sd[3][lane]);
}

// ---------------- final: red (f64) -> out = hsum@W2/N + b2 ----------------
__global__ __launch_bounds__(256) void k_final(const double* __restrict__ red,
                                               const float* __restrict__ W2,
                                               const float* __restrict__ b2,
                                               float* __restrict__ out, int N) {
    __shared__ double hs[4][64];
    const int sub = threadIdx.x >> 6;   // 0..3
    const int j   = threadIdx.x & 63;
    double s = 0.0;
    for (int p = sub; p < NRED; p += 4)
        s += red[(size_t)p * 64 + j];
    hs[sub][j] = s;
    __syncthreads();
    if (threadIdx.x < C_F) {
        int c = threadIdx.x;
        double o = 0.0;
        for (int k = 0; k < 64; ++k) {
            double hk = hs[0][k] + hs[1][k] + hs[2][k] + hs[3][k];
            o += hk * (double)W2[k * C_F + c];
        }
        out[c] = (float)(o / (double)N + (double)b2[c]);
    }
}

extern "C" void kernel_launch(void* const* d_in, const int* in_sizes, int n_in,
                              void* d_out, int out_size, void* d_ws, size_t ws_size,
                              hipStream_t stream) {
    const float* in_feat = (const float*)d_in[0];
    const int*   src     = (const int*)d_in[1];
    const int*   dst     = (const int*)d_in[2];
    const float* W1      = (const float*)d_in[3];
    const float* b1      = (const float*)d_in[4];
    const float* W2      = (const float*)d_in[5];
    const float* b2      = (const float*)d_in[6];
    float* out = (float*)d_out;

    const int N = in_sizes[0] / IN_F;           // 100000
    const int E = in_sizes[1];                  // 1600000
    const int nb = (N + BUCKET - 1) / BUCKET;   // 1563 (<= MAXB)
    const int nBin = (E + EPB - 1) / EPB;       // 196

    // ---- workspace layout (4B units) ----
    unsigned int* binnedD = (unsigned int*)d_ws;         // E
    unsigned int* binnedS = binnedD + E;                 // E
    int*   cntD   = (int*)(binnedS + E);                 // MAXB  \ zeroed
    int*   cntS   = cntD + MAXB;                         // MAXB  /
    int*   baseD  = cntS + MAXB;                         // MAXB+1
    int*   curD   = baseD + MAXB + 1;                    // MAXB
    int*   baseS  = curD + MAXB;                         // MAXB+1
    int*   curS   = baseS + MAXB + 1;                    // MAXB
    float* norm_in  = (float*)(curS + MAXB);             // N
    float* norm_out = norm_in + N;                       // N
    float* wsum     = norm_out + N;                      // N
    unsigned char* X1q = (unsigned char*)(wsum + N);     // 64N bytes
    float* partials = (float*)(X1q + 64 * (size_t)N);    // nb*64
    double* red     = (double*)(partials + (size_t)nb * 64);  // NRED*64 f64

    // only the bucket-count accumulators are read-before-write
    hipMemsetAsync(cntD, 0, 2 * MAXB * sizeof(int), stream);

    k_bhist<<<nBin, 256, 0, stream>>>(src, dst, cntS, cntD, E, nb);

    k_bucketscan2<<<1, 1024, 0, stream>>>(cntD, cntS, baseD, curD, baseS, curS, nb, E);

    k_bin2<<<nBin, 256, 0, stream>>>(src, dst, curD, curS, binnedD, binnedS, E, nb);

    k_normin<<<nb, 256, 0, stream>>>(binnedD, baseD, norm_in, N);
    k_wsum  <<<nb, 256, 0, stream>>>(binnedS, baseS, norm_in, wsum, norm_out, N);

    k_gemm1<<<(N + 63) / 64, 256, 0, stream>>>(in_feat, W1, norm_out, X1q, N);

    k_agg<<<nb, 256, 0, stream>>>(X1q, binnedD, baseD, norm_in, norm_out,
                                  wsum, b1, partials, N);

    k_red  <<<NRED, 256, 0, stream>>>(partials, red, nb);
    k_final<<<1, 256, 0, stream>>>(red, W2, b2, out, N);
}